// Round 8
// baseline (347.940 us; speedup 1.0000x reference)
//
#include <hip/hip_runtime.h>
#include <hip/hip_bf16.h>
#include <stdint.h>

// IterativeSequential2D: N=16 blocks, D=256, B=2048, ITERS=3, banded mask j<=i+1.
// bf16 MFMA (16x16x32), fp32 accumulate.
// v6: LDS stages ONLY A (v4's proven 0-conflict pipeline, counted vmcnt(4));
// W fragments are loaded per-lane directly from global (16B contiguous in k,
// L2-resident) -> per-K-step LDS traffic halves (96KB -> 48KB). Theory: v3/v4
// were LDS-port-bound (~40-79 B/cy vs 85 ceiling); v5's BK=32 swizzle was
// structurally 4-way bank-conflicted (4.9M conflicts). Fallback v2 path kept.

#define DD    256
#define NBLK  16
#define BATCH 2048

typedef __attribute__((ext_vector_type(8))) short  bf16x8;
typedef __attribute__((ext_vector_type(8))) __bf16 bfv8;
typedef __attribute__((ext_vector_type(4))) float  f32x4;

// prefix offsets of packed present blocks: P[m] = sum_{k<m} min(k+2,16); P[16]=151
__device__ __constant__ int Pofs[17] = {0,2,5,9,14,20,27,35,44,54,65,77,90,104,119,135,151};

__device__ __forceinline__ unsigned short f2bf(float f) {
  return __builtin_bit_cast(unsigned short, (__bf16)f);
}

__device__ __forceinline__ void gload_lds16(const unsigned short* g, unsigned short* l) {
  __builtin_amdgcn_global_load_lds((const __attribute__((address_space(1))) void*)g,
                                   (__attribute__((address_space(3))) void*)l, 16, 0, 0);
}

__device__ __forceinline__ bf16x8 cvt8(float4 lo, float4 hi) {
  bfv8 t;
  t[0] = (__bf16)lo.x; t[1] = (__bf16)lo.y; t[2] = (__bf16)lo.z; t[3] = (__bf16)lo.w;
  t[4] = (__bf16)hi.x; t[5] = (__bf16)hi.y; t[6] = (__bf16)hi.z; t[7] = (__bf16)hi.w;
  return __builtin_bit_cast(bf16x8, t);
}

// ---------------- pass 0 kernels ----------------

__global__ void cvt_x0_kernel(const float* __restrict__ x, unsigned short* __restrict__ y) {
  int i = blockIdx.x * 256 + threadIdx.x;   // float4 chunks, 131072 total
  float4 v = ((const float4*)x)[i];
  ushort4 o;
  o.x = f2bf(v.x); o.y = f2bf(v.y); o.z = f2bf(v.z); o.w = f2bf(v.w);
  ((ushort4*)y)[i] = o;
}

__global__ void bias_full_kernel(const float* __restrict__ b, float* __restrict__ bf) {
  int idx = blockIdx.x * 256 + threadIdx.x;  // 4096 total
  int m = idx >> 8, e = idx & 255;
  int nb = (m + 2 < NBLK) ? m + 2 : NBLK;
  float s = 0.f;
  for (int j = 0; j < nb; ++j) s += b[(m * NBLK + j) * DD + e];
  bf[idx] = s;
}

// convert present W blocks fp32 -> packed bf16. grid = 151*32 wgs of 256.
__global__ void cvt_W_kernel(const float* __restrict__ W, unsigned short* __restrict__ Wb) {
  int p = blockIdx.x >> 5;          // packed block 0..150
  int m = 0;
#pragma unroll
  for (int k = 1; k <= 15; ++k) if (p >= Pofs[k]) m = k;
  int n = p - Pofs[m];
  long idx = (long)(blockIdx.x & 31) * 2048 + threadIdx.x * 8;   // elem within 65536
  const float* src = W + (long)(m * NBLK + n) * (DD * DD) + idx;
  float4 lo = *(const float4*)src;
  float4 hi = *(const float4*)(src + 4);
  *(bf16x8*)(Wb + (long)p * (DD * DD) + idx) = cvt8(lo, hi);
}

// ---------------- main GEMM v6: A in LDS, W direct from global ----------------
// OUT_BF16=1 -> bf16 output (ws), 0 -> fp32 output (d_out)

template <int OUT_BF16>
__global__ __launch_bounds__(256, 2) void gemm_step4(
    const unsigned short* __restrict__ A,    // bf16: [B,D] (iter1) or [N,B,D]
    const unsigned short* __restrict__ Wb,   // packed bf16 blocks [151][D][D]
    const float* __restrict__ bias,          // bias[m*bias_stride + e]
    int bias_stride,
    long a_nstride,                          // elems between A n-blocks (0 or B*D)
    int nb_mode,                             // 0: nb=1; 1: nb=min(m+2,16)
    void* __restrict__ Out)
{
  __shared__ unsigned short ldsA[2][128 * 64];   // 32 KB total

  const int tid  = threadIdx.x;
  const int wave = tid >> 6;
  const int lane = tid & 63;

  // XCD-bijective swizzle (512 = 8*64) + heavy/light m pairing per XCD.
  int bid = blockIdx.x;
  int swz = (bid & 7) * 64 + (bid >> 3);
  int mi_ = swz >> 5;
  const int m = (int)((0x8796A5B4C3D2E1F0ULL >> (mi_ * 4)) & 15);  // {0,15,1,14,...}
  int rest = swz & 31;
  const int btile = rest >> 1;
  const int etile = rest & 1;
  const int nb = nb_mode ? ((m + 2 < NBLK) ? m + 2 : NBLK) : 1;
  const int nt = nb << 2;   // K-steps of 64

  const int brow0 = btile * 128;
  const int ecol0 = etile * 128;
  const int wr = (wave >> 1) & 1;
  const int wc = wave & 1;

  // --- A staging: 4 gload_lds per wave (1KB each, 8 rows), pre-swizzled src ---
  long a_goff[4];
  int  s_lds[4];
#pragma unroll
  for (int i = 0; i < 4; ++i) {
    int inst  = wave * 4 + i;
    int row   = inst * 8 + (lane >> 3);
    int chunk = (lane & 7) ^ (row & 7);
    a_goff[i] = (long)(brow0 + row) * DD + chunk * 8;
    s_lds[i]  = inst * 512;
  }

  // --- A fragment read offsets (XOR-swizzled) ---
  int offA[4][2];
#pragma unroll
  for (int f = 0; f < 4; ++f) {
    int ra = wr * 64 + f * 16 + (lane & 15);
#pragma unroll
    for (int ks = 0; ks < 2; ++ks) {
      int byteoff = ks * 64 + (lane >> 4) * 16;
      offA[f][ks] = ra * 64 + ((byteoff ^ ((ra & 7) << 4)) >> 1);
    }
  }

  f32x4 acc[4][4];
#pragma unroll
  for (int i = 0; i < 4; ++i)
#pragma unroll
    for (int j = 0; j < 4; ++j) acc[i][j] = (f32x4){0.f, 0.f, 0.f, 0.f};

  const unsigned short* Wrow = Wb + (long)Pofs[m] * (DD * DD);
  // per-lane W fragment base: row e = ecol0 + wc*64 + (lane&15), k-lane offset
  const unsigned short* Wlane =
      Wrow + (long)(ecol0 + wc * 64 + (lane & 15)) * DD + ((lane >> 4) << 3);

  auto compute = [&](int t) {
    const int p = t & 1;
    const unsigned short* Wt = Wlane + (long)(t >> 2) * (DD * DD) + (t & 3) * 64;
    bf16x8 wf[2][4];
    // issue all 8 W global loads first (compiler pipelines + inserts waits)
#pragma unroll
    for (int ks = 0; ks < 2; ++ks)
#pragma unroll
      for (int f = 0; f < 4; ++f)
        wf[ks][f] = *(const bf16x8*)(Wt + f * 16 * DD + ks * 32);
#pragma unroll
    for (int ks = 0; ks < 2; ++ks) {
      bf16x8 af[4];
#pragma unroll
      for (int f = 0; f < 4; ++f) af[f] = *(const bf16x8*)&ldsA[p][offA[f][ks]];
#pragma unroll
      for (int i = 0; i < 4; ++i)
#pragma unroll
        for (int j = 0; j < 4; ++j)
          acc[i][j] = __builtin_amdgcn_mfma_f32_16x16x32_bf16(af[i], wf[ks][j], acc[i][j], 0, 0, 0);
    }
  };

  // prologue: stage A(t=0) into buf 0 (4 gloads outstanding)
#pragma unroll
  for (int i = 0; i < 4; ++i)
    gload_lds16(A + a_goff[i], &ldsA[0][s_lds[i]]);

  // main loop: issue A(t+1), wait only the previous batch (vmcnt(4)), barrier,
  // compute (W fragments read directly from global inside), barrier.
  for (int t = 0; t < nt - 1; ++t) {
    int n2  = (t + 1) >> 2;
    int kk2 = ((t + 1) & 3) * 64;
    const unsigned short* An = A + (long)n2 * a_nstride + kk2;
    const int nxt = (t + 1) & 1;
#pragma unroll
    for (int i = 0; i < 4; ++i)
      gload_lds16(An + a_goff[i], &ldsA[nxt][s_lds[i]]);
    asm volatile("s_waitcnt vmcnt(4)" ::: "memory");
    __builtin_amdgcn_s_barrier();
    compute(t);
    __builtin_amdgcn_s_barrier();
  }
  // final iteration: drain, no prefetch.
  asm volatile("s_waitcnt vmcnt(0)" ::: "memory");
  __builtin_amdgcn_s_barrier();
  compute(nt - 1);

  // epilogue: bias + relu + store, j innermost (4 stores per 128B line).
  const long outbase = (long)m * BATCH * DD;
  const int  rowbase = brow0 + wr * 64;
  const int  colbase = ecol0 + wc * 64;
  float bv[4];
#pragma unroll
  for (int j = 0; j < 4; ++j)
    bv[j] = bias[m * bias_stride + colbase + j * 16 + (lane & 15)];
#pragma unroll
  for (int i = 0; i < 4; ++i) {
#pragma unroll
    for (int r = 0; r < 4; ++r) {
      const int row = rowbase + i * 16 + ((lane >> 4) << 2) + r;
      const long rb = outbase + (long)row * DD + colbase + (lane & 15);
#pragma unroll
      for (int j = 0; j < 4; ++j) {
        float v = acc[i][j][r] + bv[j];
        v = v > 0.f ? v : 0.f;
        if (OUT_BF16) ((unsigned short*)Out)[rb + j * 16] = f2bf(v);
        else          ((float*)Out)[rb + j * 16] = v;
      }
    }
  }
}

// ---------------- fallback GEMM (v2, fp32 W) ----------------

template <int OUT_BF16>
__global__ __launch_bounds__(256, 2) void gemm_step(
    const unsigned short* __restrict__ A,
    const float* __restrict__ Wg,
    const float* __restrict__ bias,
    int bias_stride, long a_nstride, int nb_mode,
    void* __restrict__ Out)
{
  __shared__ unsigned short ldsA[2][128 * 64];
  __shared__ unsigned short ldsW[2][128 * 64];
  const int tid  = threadIdx.x;
  const int wave = tid >> 6;
  const int lane = tid & 63;
  int bid = blockIdx.x;
  int swz = (bid & 7) * 64 + (bid >> 3);
  int mi_ = swz >> 5;
  const int m = (int)((0x8796A5B4C3D2E1F0ULL >> (mi_ * 4)) & 15);
  int rest = swz & 31;
  const int btile = rest >> 1;
  const int etile = rest & 1;
  const int nb = nb_mode ? ((m + 2 < NBLK) ? m + 2 : NBLK) : 1;
  const int nt = nb << 2;
  const int brow0 = btile * 128;
  const int ecol0 = etile * 128;
  const int wr = (wave >> 1) & 1;
  const int wc = wave & 1;

  long a_goff[4]; int a_lds[4];
#pragma unroll
  for (int i = 0; i < 4; ++i) {
    int inst  = wave * 4 + i;
    int row   = inst * 8 + (lane >> 3);
    int chunk = (lane & 7) ^ (row & 7);
    a_goff[i] = (long)(brow0 + row) * DD + chunk * 8;
    a_lds[i]  = inst * 512;
  }
  long w_goff[4]; int w_lds[4];
#pragma unroll
  for (int u = 0; u < 4; ++u) {
    int cid = tid + 256 * u;
    int row = cid >> 3;
    int c16 = cid & 7;
    w_goff[u] = (long)(ecol0 + row) * DD + c16 * 8;
    w_lds[u]  = row * 64 + ((c16 ^ (row & 7)) * 8);
  }
  int offA[4][2], offW[4][2];
#pragma unroll
  for (int f = 0; f < 4; ++f) {
    int ra = wr * 64 + f * 16 + (lane & 15);
    int rw = wc * 64 + f * 16 + (lane & 15);
#pragma unroll
    for (int ks = 0; ks < 2; ++ks) {
      int byteoff = ks * 64 + (lane >> 4) * 16;
      offA[f][ks] = ra * 64 + ((byteoff ^ ((ra & 7) << 4)) >> 1);
      offW[f][ks] = rw * 64 + ((byteoff ^ ((rw & 7) << 4)) >> 1);
    }
  }
  f32x4 acc[4][4];
#pragma unroll
  for (int i = 0; i < 4; ++i)
#pragma unroll
    for (int j = 0; j < 4; ++j) acc[i][j] = (f32x4){0.f,0.f,0.f,0.f};
  const long wm_base = (long)m * NBLK * (DD * DD);
  {
#pragma unroll
    for (int i = 0; i < 4; ++i) gload_lds16(A + a_goff[i], &ldsA[0][a_lds[i]]);
    const float* Wn = Wg + wm_base;
#pragma unroll
    for (int u = 0; u < 4; ++u) {
      float4 lo = *(const float4*)(Wn + w_goff[u]);
      float4 hi = *(const float4*)(Wn + w_goff[u] + 4);
      *(bf16x8*)&ldsW[0][w_lds[u]] = cvt8(lo, hi);
    }
  }
  __syncthreads();
  int cur = 0;
  for (int t = 0; t < nt; ++t) {
    const int nxt = cur ^ 1;
    const bool has_next = (t + 1 < nt);
    float4 wlo[4], whi[4];
    if (has_next) {
      int n2  = (t + 1) >> 2;
      int kk2 = ((t + 1) & 3) * 64;
      const unsigned short* An = A + (long)n2 * a_nstride + kk2;
#pragma unroll
      for (int i = 0; i < 4; ++i) gload_lds16(An + a_goff[i], &ldsA[nxt][a_lds[i]]);
      const float* Wn = Wg + wm_base + (long)n2 * (DD * DD) + kk2;
#pragma unroll
      for (int u = 0; u < 4; ++u) {
        wlo[u] = *(const float4*)(Wn + w_goff[u]);
        whi[u] = *(const float4*)(Wn + w_goff[u] + 4);
      }
    }
#pragma unroll
    for (int ks = 0; ks < 2; ++ks) {
      bf16x8 af[4], wf[4];
#pragma unroll
      for (int f = 0; f < 4; ++f) af[f] = *(const bf16x8*)&ldsA[cur][offA[f][ks]];
#pragma unroll
      for (int f = 0; f < 4; ++f) wf[f] = *(const bf16x8*)&ldsW[cur][offW[f][ks]];
#pragma unroll
      for (int i = 0; i < 4; ++i)
#pragma unroll
        for (int j = 0; j < 4; ++j)
          acc[i][j] = __builtin_amdgcn_mfma_f32_16x16x32_bf16(af[i], wf[j], acc[i][j], 0, 0, 0);
    }
    if (has_next) {
#pragma unroll
      for (int u = 0; u < 4; ++u)
        *(bf16x8*)&ldsW[nxt][w_lds[u]] = cvt8(wlo[u], whi[u]);
    }
    __syncthreads();
    cur = nxt;
  }
  const long outbase = (long)m * BATCH * DD;
  const int  rowbase = brow0 + wr * 64;
  const int  colbase = ecol0 + wc * 64;
#pragma unroll
  for (int j = 0; j < 4; ++j) {
    const int col = colbase + j * 16 + (lane & 15);
    const float bv = bias[m * bias_stride + col];
#pragma unroll
    for (int i = 0; i < 4; ++i) {
      const int row0 = rowbase + i * 16 + ((lane >> 4) << 2);
#pragma unroll
      for (int r = 0; r < 4; ++r) {
        float v = acc[i][j][r] + bv;
        v = v > 0.f ? v : 0.f;
        long idx = outbase + (long)(row0 + r) * DD + col;
        if (OUT_BF16) ((unsigned short*)Out)[idx] = f2bf(v);
        else          ((float*)Out)[idx] = v;
      }
    }
  }
}

// ---------------- launcher ----------------

extern "C" void kernel_launch(void* const* d_in, const int* in_sizes, int n_in,
                              void* d_out, int out_size, void* d_ws, size_t ws_size,
                              hipStream_t stream) {
  const float* x0 = (const float*)d_in[0];
  const float* W  = (const float*)d_in[1];
  const float* b  = (const float*)d_in[2];
  float* out = (float*)d_out;

  char* ws = (char*)d_ws;
  unsigned short* x0b = (unsigned short*)ws;                    // 1 MB
  unsigned short* Y0  = (unsigned short*)(ws + (1ull << 20));   // 16 MB
  unsigned short* Y1  = (unsigned short*)(ws + (17ull << 20));  // 16 MB

  const size_t wb_bytes = 151ull * DD * DD * 2;                 // 18.9 MB
  const size_t need = (33ull << 20) + wb_bytes + 16384;

  cvt_x0_kernel<<<512, 256, 0, stream>>>(x0, x0b);

  if (ws_size >= need) {
    unsigned short* Wb = (unsigned short*)(ws + (33ull << 20));
    float* bias_full   = (float*)(ws + (33ull << 20) + wb_bytes);
    bias_full_kernel<<<16, 256, 0, stream>>>(b, bias_full);
    cvt_W_kernel<<<151 * 32, 256, 0, stream>>>(W, Wb);
    gemm_step4<1><<<512, 256, 0, stream>>>(x0b, Wb, b, NBLK * DD, 0L, 0, (void*)Y0);
    gemm_step4<1><<<512, 256, 0, stream>>>(Y0, Wb, bias_full, DD, (long)BATCH * DD, 1, (void*)Y1);
    gemm_step4<0><<<512, 256, 0, stream>>>(Y1, Wb, bias_full, DD, (long)BATCH * DD, 1, (void*)out);
  } else {
    float* bias_full = (float*)(ws + (33ull << 20));
    bias_full_kernel<<<16, 256, 0, stream>>>(b, bias_full);
    gemm_step<1><<<512, 256, 0, stream>>>(x0b, W, b, NBLK * DD, 0L, 0, (void*)Y0);
    gemm_step<1><<<512, 256, 0, stream>>>(Y0, W, bias_full, DD, (long)BATCH * DD, 1, (void*)Y1);
    gemm_step<0><<<512, 256, 0, stream>>>(Y1, W, bias_full, DD, (long)BATCH * DD, 1, (void*)out);
  }
}

// Round 10
// 312.045 us; speedup vs baseline: 1.1150x; 1.1150x over previous
//
#include <hip/hip_runtime.h>
#include <hip/hip_bf16.h>
#include <stdint.h>

// IterativeSequential2D: N=16 blocks, D=256, B=2048, ITERS=3, banded mask j<=i+1.
// bf16 MFMA (16x16x32), fp32 accumulate.
// v7: A staged in LDS (v4's proven 0-conflict counted-vmcnt pipeline, 32 KB);
// W fragments double-buffered in REGISTERS (wfA/wfB, pair-unrolled: rule #20)
// and prefetched one K-step ahead, issued BEFORE the vmcnt+barrier so the
// ~200-400cy L2 latency hides under the previous step's MFMA (fixes v6's
// exposed-latency regression). Per-step LDS traffic 96KB -> 48KB.
// Fallback v2 path kept for small ws.

#define DD    256
#define NBLK  16
#define BATCH 2048

typedef __attribute__((ext_vector_type(8))) short  bf16x8;
typedef __attribute__((ext_vector_type(8))) __bf16 bfv8;
typedef __attribute__((ext_vector_type(4))) float  f32x4;

// prefix offsets of packed present blocks: P[m] = sum_{k<m} min(k+2,16); P[16]=151
__device__ __constant__ int Pofs[17] = {0,2,5,9,14,20,27,35,44,54,65,77,90,104,119,135,151};

__device__ __forceinline__ unsigned short f2bf(float f) {
  return __builtin_bit_cast(unsigned short, (__bf16)f);
}

__device__ __forceinline__ void gload_lds16(const unsigned short* g, unsigned short* l) {
  __builtin_amdgcn_global_load_lds((const __attribute__((address_space(1))) void*)g,
                                   (__attribute__((address_space(3))) void*)l, 16, 0, 0);
}

__device__ __forceinline__ bf16x8 cvt8(float4 lo, float4 hi) {
  bfv8 t;
  t[0] = (__bf16)lo.x; t[1] = (__bf16)lo.y; t[2] = (__bf16)lo.z; t[3] = (__bf16)lo.w;
  t[4] = (__bf16)hi.x; t[5] = (__bf16)hi.y; t[6] = (__bf16)hi.z; t[7] = (__bf16)hi.w;
  return __builtin_bit_cast(bf16x8, t);
}

// ---------------- pass 0 kernels ----------------

__global__ void cvt_x0_kernel(const float* __restrict__ x, unsigned short* __restrict__ y) {
  int i = blockIdx.x * 256 + threadIdx.x;   // float4 chunks, 131072 total
  float4 v = ((const float4*)x)[i];
  ushort4 o;
  o.x = f2bf(v.x); o.y = f2bf(v.y); o.z = f2bf(v.z); o.w = f2bf(v.w);
  ((ushort4*)y)[i] = o;
}

__global__ void bias_full_kernel(const float* __restrict__ b, float* __restrict__ bf) {
  int idx = blockIdx.x * 256 + threadIdx.x;  // 4096 total
  int m = idx >> 8, e = idx & 255;
  int nb = (m + 2 < NBLK) ? m + 2 : NBLK;
  float s = 0.f;
  for (int j = 0; j < nb; ++j) s += b[(m * NBLK + j) * DD + e];
  bf[idx] = s;
}

// convert present W blocks fp32 -> packed bf16. grid = 151*32 wgs of 256.
__global__ void cvt_W_kernel(const float* __restrict__ W, unsigned short* __restrict__ Wb) {
  int p = blockIdx.x >> 5;          // packed block 0..150
  int m = 0;
#pragma unroll
  for (int k = 1; k <= 15; ++k) if (p >= Pofs[k]) m = k;
  int n = p - Pofs[m];
  long idx = (long)(blockIdx.x & 31) * 2048 + threadIdx.x * 8;   // elem within 65536
  const float* src = W + (long)(m * NBLK + n) * (DD * DD) + idx;
  float4 lo = *(const float4*)src;
  float4 hi = *(const float4*)(src + 4);
  *(bf16x8*)(Wb + (long)p * (DD * DD) + idx) = cvt8(lo, hi);
}

// ------------- main GEMM v7: A in LDS, W in prefetched registers -------------
// OUT_BF16=1 -> bf16 output (ws), 0 -> fp32 output (d_out)

template <int OUT_BF16>
__global__ __launch_bounds__(256, 2) void gemm_step5(
    const unsigned short* __restrict__ A,    // bf16: [B,D] (iter1) or [N,B,D]
    const unsigned short* __restrict__ Wb,   // packed bf16 blocks [151][D][D]
    const float* __restrict__ bias,          // bias[m*bias_stride + e]
    int bias_stride,
    long a_nstride,                          // elems between A n-blocks (0 or B*D)
    int nb_mode,                             // 0: nb=1; 1: nb=min(m+2,16)
    void* __restrict__ Out)
{
  __shared__ unsigned short ldsA[2][128 * 64];   // 32 KB

  const int tid  = threadIdx.x;
  const int wave = tid >> 6;
  const int lane = tid & 63;

  // XCD-bijective swizzle (512 = 8*64) + heavy/light m pairing per XCD.
  int bid = blockIdx.x;
  int swz = (bid & 7) * 64 + (bid >> 3);
  int mi_ = swz >> 5;
  const int m = (int)((0x8796A5B4C3D2E1F0ULL >> (mi_ * 4)) & 15);  // {0,15,1,14,...}
  int rest = swz & 31;
  const int btile = rest >> 1;
  const int etile = rest & 1;
  const int nb = nb_mode ? ((m + 2 < NBLK) ? m + 2 : NBLK) : 1;
  const int nt = nb << 2;   // K-steps of 64, nt >= 4, always even

  const int brow0 = btile * 128;
  const int ecol0 = etile * 128;
  const int wr = (wave >> 1) & 1;
  const int wc = wave & 1;

  // --- A staging: 4 gload_lds per wave (1KB each, 8 rows), pre-swizzled src ---
  long a_goff[4];
  int  s_lds[4];
#pragma unroll
  for (int i = 0; i < 4; ++i) {
    int inst  = wave * 4 + i;
    int row   = inst * 8 + (lane >> 3);
    int chunk = (lane & 7) ^ (row & 7);
    a_goff[i] = (long)(brow0 + row) * DD + chunk * 8;
    s_lds[i]  = inst * 512;
  }

  // --- A fragment read offsets (XOR-swizzled) ---
  int offA[4][2];
#pragma unroll
  for (int f = 0; f < 4; ++f) {
    int ra = wr * 64 + f * 16 + (lane & 15);
#pragma unroll
    for (int ks = 0; ks < 2; ++ks) {
      int byteoff = ks * 64 + (lane >> 4) * 16;
      offA[f][ks] = ra * 64 + ((byteoff ^ ((ra & 7) << 4)) >> 1);
    }
  }

  f32x4 acc[4][4];
#pragma unroll
  for (int i = 0; i < 4; ++i)
#pragma unroll
    for (int j = 0; j < 4; ++j) acc[i][j] = (f32x4){0.f, 0.f, 0.f, 0.f};

  const unsigned short* Wrow = Wb + (long)Pofs[m] * (DD * DD);
  // per-lane W fragment base: row e = ecol0 + wc*64 + (lane&15), k-lane offset
  const unsigned short* Wlane =
      Wrow + (long)(ecol0 + wc * 64 + (lane & 15)) * DD + ((lane >> 4) << 3);

  // W register double-buffers (named, compile-time indexed: rule #20)
  bf16x8 wfA[2][4], wfB[2][4];

  auto loadW = [&](bf16x8 (&wf)[2][4], int t) {
    const unsigned short* Wt = Wlane + (long)(t >> 2) * (DD * DD) + (t & 3) * 64;
#pragma unroll
    for (int ks = 0; ks < 2; ++ks)
#pragma unroll
      for (int f = 0; f < 4; ++f)
        wf[ks][f] = *(const bf16x8*)(Wt + f * 16 * DD + ks * 32);
  };

  auto issueA = [&](int t) {
    int n2  = t >> 2;
    int kk2 = (t & 3) * 64;
    const unsigned short* An = A + (long)n2 * a_nstride + kk2;
    unsigned short* lb = &ldsA[t & 1][0];
#pragma unroll
    for (int i = 0; i < 4; ++i)
      gload_lds16(An + a_goff[i], lb + s_lds[i]);
  };

  auto computeT = [&](bf16x8 (&wf)[2][4], int t) {
    const unsigned short* lb = &ldsA[t & 1][0];
#pragma unroll
    for (int ks = 0; ks < 2; ++ks) {
      bf16x8 af[4];
#pragma unroll
      for (int f = 0; f < 4; ++f) af[f] = *(const bf16x8*)(lb + offA[f][ks]);
#pragma unroll
      for (int i = 0; i < 4; ++i)
#pragma unroll
        for (int j = 0; j < 4; ++j)
          acc[i][j] = __builtin_amdgcn_mfma_f32_16x16x32_bf16(af[i], wf[ks][j], acc[i][j], 0, 0, 0);
    }
  };

  // prologue: step 0 in flight (4 A-gloads + 8 W-loads)
  issueA(0); loadW(wfA, 0);

  // pair-unrolled main loop; nt is even, runs t = 0,2,...,nt-4.
  // Each half: issue next step's A+W (12 loads), wait ONLY the previous
  // step's 12 (vmcnt(12)), barrier, MFMA, barrier.
  int t = 0;
  for (; t < nt - 2; t += 2) {
    issueA(t + 1); loadW(wfB, t + 1);
    asm volatile("s_waitcnt vmcnt(12)" ::: "memory");
    __builtin_amdgcn_s_barrier();
    computeT(wfA, t);
    __builtin_amdgcn_s_barrier();

    issueA(t + 2); loadW(wfA, t + 2);
    asm volatile("s_waitcnt vmcnt(12)" ::: "memory");
    __builtin_amdgcn_s_barrier();
    computeT(wfB, t + 1);
    __builtin_amdgcn_s_barrier();
  }
  // t == nt-2: last prefetch + two peeled computes
  issueA(nt - 1); loadW(wfB, nt - 1);
  asm volatile("s_waitcnt vmcnt(12)" ::: "memory");
  __builtin_amdgcn_s_barrier();
  computeT(wfA, nt - 2);
  __builtin_amdgcn_s_barrier();
  asm volatile("s_waitcnt vmcnt(0)" ::: "memory");
  __builtin_amdgcn_s_barrier();
  computeT(wfB, nt - 1);

  // epilogue: bias + relu + store, j innermost (4 stores per 128B line).
  const long outbase = (long)m * BATCH * DD;
  const int  rowbase = brow0 + wr * 64;
  const int  colbase = ecol0 + wc * 64;
  float bv[4];
#pragma unroll
  for (int j = 0; j < 4; ++j)
    bv[j] = bias[m * bias_stride + colbase + j * 16 + (lane & 15)];
#pragma unroll
  for (int i = 0; i < 4; ++i) {
#pragma unroll
    for (int r = 0; r < 4; ++r) {
      const int row = rowbase + i * 16 + ((lane >> 4) << 2) + r;
      const long rb = outbase + (long)row * DD + colbase + (lane & 15);
#pragma unroll
      for (int j = 0; j < 4; ++j) {
        float v = acc[i][j][r] + bv[j];
        v = v > 0.f ? v : 0.f;
        if (OUT_BF16) ((unsigned short*)Out)[rb + j * 16] = f2bf(v);
        else          ((float*)Out)[rb + j * 16] = v;
      }
    }
  }
}

// ---------------- fallback GEMM (v2, fp32 W) ----------------

template <int OUT_BF16>
__global__ __launch_bounds__(256, 2) void gemm_step(
    const unsigned short* __restrict__ A,
    const float* __restrict__ Wg,
    const float* __restrict__ bias,
    int bias_stride, long a_nstride, int nb_mode,
    void* __restrict__ Out)
{
  __shared__ unsigned short ldsA[2][128 * 64];
  __shared__ unsigned short ldsW[2][128 * 64];
  const int tid  = threadIdx.x;
  const int wave = tid >> 6;
  const int lane = tid & 63;
  int bid = blockIdx.x;
  int swz = (bid & 7) * 64 + (bid >> 3);
  int mi_ = swz >> 5;
  const int m = (int)((0x8796A5B4C3D2E1F0ULL >> (mi_ * 4)) & 15);
  int rest = swz & 31;
  const int btile = rest >> 1;
  const int etile = rest & 1;
  const int nb = nb_mode ? ((m + 2 < NBLK) ? m + 2 : NBLK) : 1;
  const int nt = nb << 2;
  const int brow0 = btile * 128;
  const int ecol0 = etile * 128;
  const int wr = (wave >> 1) & 1;
  const int wc = wave & 1;

  long a_goff[4]; int a_lds[4];
#pragma unroll
  for (int i = 0; i < 4; ++i) {
    int inst  = wave * 4 + i;
    int row   = inst * 8 + (lane >> 3);
    int chunk = (lane & 7) ^ (row & 7);
    a_goff[i] = (long)(brow0 + row) * DD + chunk * 8;
    a_lds[i]  = inst * 512;
  }
  long w_goff[4]; int w_lds[4];
#pragma unroll
  for (int u = 0; u < 4; ++u) {
    int cid = tid + 256 * u;
    int row = cid >> 3;
    int c16 = cid & 7;
    w_goff[u] = (long)(ecol0 + row) * DD + c16 * 8;
    w_lds[u]  = row * 64 + ((c16 ^ (row & 7)) * 8);
  }
  int offA[4][2], offW[4][2];
#pragma unroll
  for (int f = 0; f < 4; ++f) {
    int ra = wr * 64 + f * 16 + (lane & 15);
    int rw = wc * 64 + f * 16 + (lane & 15);
#pragma unroll
    for (int ks = 0; ks < 2; ++ks) {
      int byteoff = ks * 64 + (lane >> 4) * 16;
      offA[f][ks] = ra * 64 + ((byteoff ^ ((ra & 7) << 4)) >> 1);
      offW[f][ks] = rw * 64 + ((byteoff ^ ((rw & 7) << 4)) >> 1);
    }
  }
  f32x4 acc[4][4];
#pragma unroll
  for (int i = 0; i < 4; ++i)
#pragma unroll
    for (int j = 0; j < 4; ++j) acc[i][j] = (f32x4){0.f,0.f,0.f,0.f};
  const long wm_base = (long)m * NBLK * (DD * DD);
  {
#pragma unroll
    for (int i = 0; i < 4; ++i) gload_lds16(A + a_goff[i], &ldsA[0][a_lds[i]]);
    const float* Wn = Wg + wm_base;
#pragma unroll
    for (int u = 0; u < 4; ++u) {
      float4 lo = *(const float4*)(Wn + w_goff[u]);
      float4 hi = *(const float4*)(Wn + w_goff[u] + 4);
      *(bf16x8*)&ldsW[0][w_lds[u]] = cvt8(lo, hi);
    }
  }
  __syncthreads();
  int cur = 0;
  for (int t = 0; t < nt; ++t) {
    const int nxt = cur ^ 1;
    const bool has_next = (t + 1 < nt);
    float4 wlo[4], whi[4];
    if (has_next) {
      int n2  = (t + 1) >> 2;
      int kk2 = ((t + 1) & 3) * 64;
      const unsigned short* An = A + (long)n2 * a_nstride + kk2;
#pragma unroll
      for (int i = 0; i < 4; ++i) gload_lds16(An + a_goff[i], &ldsA[nxt][a_lds[i]]);
      const float* Wn = Wg + wm_base + (long)n2 * (DD * DD) + kk2;
#pragma unroll
      for (int u = 0; u < 4; ++u) {
        wlo[u] = *(const float4*)(Wn + w_goff[u]);
        whi[u] = *(const float4*)(Wn + w_goff[u] + 4);
      }
    }
#pragma unroll
    for (int ks = 0; ks < 2; ++ks) {
      bf16x8 af[4], wf[4];
#pragma unroll
      for (int f = 0; f < 4; ++f) af[f] = *(const bf16x8*)&ldsA[cur][offA[f][ks]];
#pragma unroll
      for (int f = 0; f < 4; ++f) wf[f] = *(const bf16x8*)&ldsW[cur][offW[f][ks]];
#pragma unroll
      for (int i = 0; i < 4; ++i)
#pragma unroll
        for (int j = 0; j < 4; ++j)
          acc[i][j] = __builtin_amdgcn_mfma_f32_16x16x32_bf16(af[i], wf[j], acc[i][j], 0, 0, 0);
    }
    if (has_next) {
#pragma unroll
      for (int u = 0; u < 4; ++u)
        *(bf16x8*)&ldsW[nxt][w_lds[u]] = cvt8(wlo[u], whi[u]);
    }
    __syncthreads();
    cur = nxt;
  }
  const long outbase = (long)m * BATCH * DD;
  const int  rowbase = brow0 + wr * 64;
  const int  colbase = ecol0 + wc * 64;
#pragma unroll
  for (int j = 0; j < 4; ++j) {
    const int col = colbase + j * 16 + (lane & 15);
    const float bv = bias[m * bias_stride + col];
#pragma unroll
    for (int i = 0; i < 4; ++i) {
      const int row0 = rowbase + i * 16 + ((lane >> 4) << 2);
#pragma unroll
      for (int r = 0; r < 4; ++r) {
        float v = acc[i][j][r] + bv;
        v = v > 0.f ? v : 0.f;
        long idx = outbase + (long)(row0 + r) * DD + col;
        if (OUT_BF16) ((unsigned short*)Out)[idx] = f2bf(v);
        else          ((float*)Out)[idx] = v;
      }
    }
  }
}

// ---------------- launcher ----------------

extern "C" void kernel_launch(void* const* d_in, const int* in_sizes, int n_in,
                              void* d_out, int out_size, void* d_ws, size_t ws_size,
                              hipStream_t stream) {
  const float* x0 = (const float*)d_in[0];
  const float* W  = (const float*)d_in[1];
  const float* b  = (const float*)d_in[2];
  float* out = (float*)d_out;

  char* ws = (char*)d_ws;
  unsigned short* x0b = (unsigned short*)ws;                    // 1 MB
  unsigned short* Y0  = (unsigned short*)(ws + (1ull << 20));   // 16 MB
  unsigned short* Y1  = (unsigned short*)(ws + (17ull << 20));  // 16 MB

  const size_t wb_bytes = 151ull * DD * DD * 2;                 // 18.9 MB
  const size_t need = (33ull << 20) + wb_bytes + 16384;

  cvt_x0_kernel<<<512, 256, 0, stream>>>(x0, x0b);

  if (ws_size >= need) {
    unsigned short* Wb = (unsigned short*)(ws + (33ull << 20));
    float* bias_full   = (float*)(ws + (33ull << 20) + wb_bytes);
    bias_full_kernel<<<16, 256, 0, stream>>>(b, bias_full);
    cvt_W_kernel<<<151 * 32, 256, 0, stream>>>(W, Wb);
    gemm_step5<1><<<512, 256, 0, stream>>>(x0b, Wb, b, NBLK * DD, 0L, 0, (void*)Y0);
    gemm_step5<1><<<512, 256, 0, stream>>>(Y0, Wb, bias_full, DD, (long)BATCH * DD, 1, (void*)Y1);
    gemm_step5<0><<<512, 256, 0, stream>>>(Y1, Wb, bias_full, DD, (long)BATCH * DD, 1, (void*)out);
  } else {
    float* bias_full = (float*)(ws + (33ull << 20));
    bias_full_kernel<<<16, 256, 0, stream>>>(b, bias_full);
    gemm_step<1><<<512, 256, 0, stream>>>(x0b, W, b, NBLK * DD, 0L, 0, (void*)Y0);
    gemm_step<1><<<512, 256, 0, stream>>>(Y0, W, bias_full, DD, (long)BATCH * DD, 1, (void*)Y1);
    gemm_step<0><<<512, 256, 0, stream>>>(Y1, W, bias_full, DD, (long)BATCH * DD, 1, (void*)out);
  }
}

// Round 12
// 268.118 us; speedup vs baseline: 1.2977x; 1.1638x over previous
//
#include <hip/hip_runtime.h>
#include <hip/hip_bf16.h>
#include <stdint.h>

// IterativeSequential2D: N=16 blocks, D=256, B=2048, ITERS=3, banded mask j<=i+1.
// bf16 MFMA (16x16x32), fp32 accumulate.
// v8: split-K. Each m-row split into units of <=8 n-blocks (max 32 K-steps vs 64).
// 25 units x 32 tiles = 800 blocks, dynamic backfill. Split rows (m>=7) write raw
// fp32 partials (18 x 2MB ws slots); combine kernel applies sum+bias+relu.
// Inner loop identical to proven v4 (gload_lds both operands, vmcnt(8) counted).
// Per-iter template TAG gives distinct kernel names for per-dispatch profiling.
// Tiered fallback: ws < 89MB -> proven v4 path.

#define DD    256
#define NBLK  16
#define BATCH 2048
#define BD    (BATCH * DD)

typedef __attribute__((ext_vector_type(8))) short  bf16x8;
typedef __attribute__((ext_vector_type(8))) __bf16 bfv8;
typedef __attribute__((ext_vector_type(4))) float  f32x4;

// prefix offsets of packed present blocks: P[m] = sum_{k<m} min(k+2,16); P[16]=151
__device__ __constant__ int Pofs[17] = {0,2,5,9,14,20,27,35,44,54,65,77,90,104,119,135,151};

// split-K unit table: {m, n0, nn, slot(-1=direct)} ; heavy/light interleaved for balance
__device__ __constant__ int unit_tbl[25][4] = {
  {6,0,8,-1},{0,0,2,-1},{13,0,8,12},{1,0,3,-1},{14,0,8,14},{2,0,4,-1},{14,8,8,15},
  {7,5,4,1},{15,0,8,16},{3,0,5,-1},{15,8,8,17},{7,0,5,0},{5,0,7,-1},{8,0,5,2},
  {11,0,7,8},{8,5,5,3},{12,0,7,10},{9,6,5,5},{12,7,7,11},{4,0,6,-1},{13,8,7,13},
  {9,0,6,4},{10,0,6,6},{10,6,6,7},{11,7,6,9}
};

__device__ __forceinline__ unsigned short f2bf(float f) {
  return __builtin_bit_cast(unsigned short, (__bf16)f);
}

__device__ __forceinline__ void gload_lds16(const unsigned short* g, unsigned short* l) {
  __builtin_amdgcn_global_load_lds((const __attribute__((address_space(1))) void*)g,
                                   (__attribute__((address_space(3))) void*)l, 16, 0, 0);
}

__device__ __forceinline__ bf16x8 cvt8(float4 lo, float4 hi) {
  bfv8 t;
  t[0] = (__bf16)lo.x; t[1] = (__bf16)lo.y; t[2] = (__bf16)lo.z; t[3] = (__bf16)lo.w;
  t[4] = (__bf16)hi.x; t[5] = (__bf16)hi.y; t[6] = (__bf16)hi.z; t[7] = (__bf16)hi.w;
  return __builtin_bit_cast(bf16x8, t);
}

// ---------------- pass 0 kernels ----------------

__global__ void cvt_x0_kernel(const float* __restrict__ x, unsigned short* __restrict__ y) {
  int i = blockIdx.x * 256 + threadIdx.x;
  float4 v = ((const float4*)x)[i];
  ushort4 o;
  o.x = f2bf(v.x); o.y = f2bf(v.y); o.z = f2bf(v.z); o.w = f2bf(v.w);
  ((ushort4*)y)[i] = o;
}

__global__ void bias_full_kernel(const float* __restrict__ b, float* __restrict__ bf) {
  int idx = blockIdx.x * 256 + threadIdx.x;
  int m = idx >> 8, e = idx & 255;
  int nb = (m + 2 < NBLK) ? m + 2 : NBLK;
  float s = 0.f;
  for (int j = 0; j < nb; ++j) s += b[(m * NBLK + j) * DD + e];
  bf[idx] = s;
}

__global__ void cvt_W_kernel(const float* __restrict__ W, unsigned short* __restrict__ Wb) {
  int p = blockIdx.x >> 5;
  int m = 0;
#pragma unroll
  for (int k = 1; k <= 15; ++k) if (p >= Pofs[k]) m = k;
  int n = p - Pofs[m];
  long idx = (long)(blockIdx.x & 31) * 2048 + threadIdx.x * 8;
  const float* src = W + (long)(m * NBLK + n) * (DD * DD) + idx;
  float4 lo = *(const float4*)src;
  float4 hi = *(const float4*)(src + 4);
  *(bf16x8*)(Wb + (long)p * (DD * DD) + idx) = cvt8(lo, hi);
}

// -------- split-K unit GEMM (v4-proven inner loop), grid 800 --------
// OUT_BF16: direct-unit output dtype (1=bf16 to Y, 0=fp32 to d_out).

template <int OUT_BF16, int TAG>
__global__ __launch_bounds__(256, 2) void gemm_unit(
    const unsigned short* __restrict__ A,    // bf16 [N,B,D]
    const unsigned short* __restrict__ Wb,   // packed bf16 blocks [151][D][D]
    const float* __restrict__ bias_full,     // [N,D]
    float* __restrict__ P,                   // partial slots [18][B,D]
    void* __restrict__ Out)
{
  __shared__ unsigned short ldsA[2][128 * 64];
  __shared__ unsigned short ldsW[2][128 * 64];

  const int tid  = threadIdx.x;
  const int wave = tid >> 6;
  const int lane = tid & 63;

  // bijective XCD swizzle: 800 = 8 * 100
  int bid = blockIdx.x;
  int swz = (bid & 7) * 100 + (bid >> 3);
  const int u     = swz >> 5;     // 0..24
  const int tile  = swz & 31;
  const int m    = unit_tbl[u][0];
  const int n0   = unit_tbl[u][1];
  const int nn   = unit_tbl[u][2];
  const int slot = unit_tbl[u][3];
  const int nt   = nn << 2;       // K-steps of 64, 8..32

  const int btile = tile >> 1;
  const int etile = tile & 1;
  const int brow0 = btile * 128;
  const int ecol0 = etile * 128;
  const int wr = (wave >> 1) & 1;
  const int wc = wave & 1;

  long a_goff[4], w_goff[4];
  int  s_lds[4];
#pragma unroll
  for (int i = 0; i < 4; ++i) {
    int inst  = wave * 4 + i;
    int row   = inst * 8 + (lane >> 3);
    int chunk = (lane & 7) ^ (row & 7);
    a_goff[i] = (long)(brow0 + row) * DD + chunk * 8;
    w_goff[i] = (long)(ecol0 + row) * DD + chunk * 8;
    s_lds[i]  = inst * 512;
  }

  int offA[4][2], offW[4][2];
#pragma unroll
  for (int f = 0; f < 4; ++f) {
    int ra = wr * 64 + f * 16 + (lane & 15);
    int rw = wc * 64 + f * 16 + (lane & 15);
#pragma unroll
    for (int ks = 0; ks < 2; ++ks) {
      int byteoff = ks * 64 + (lane >> 4) * 16;
      offA[f][ks] = ra * 64 + ((byteoff ^ ((ra & 7) << 4)) >> 1);
      offW[f][ks] = rw * 64 + ((byteoff ^ ((rw & 7) << 4)) >> 1);
    }
  }

  f32x4 acc[4][4];
#pragma unroll
  for (int i = 0; i < 4; ++i)
#pragma unroll
    for (int j = 0; j < 4; ++j) acc[i][j] = (f32x4){0.f, 0.f, 0.f, 0.f};

  const unsigned short* Wrow = Wb + (long)(Pofs[m] + n0) * (DD * DD);
  const unsigned short* A0   = A + (long)n0 * BD;

  auto compute = [&](int p) {
#pragma unroll
    for (int ks = 0; ks < 2; ++ks) {
      bf16x8 af[4], wf[4];
#pragma unroll
      for (int f = 0; f < 4; ++f) af[f] = *(const bf16x8*)&ldsA[p][offA[f][ks]];
#pragma unroll
      for (int f = 0; f < 4; ++f) wf[f] = *(const bf16x8*)&ldsW[p][offW[f][ks]];
#pragma unroll
      for (int i = 0; i < 4; ++i)
#pragma unroll
        for (int j = 0; j < 4; ++j)
          acc[i][j] = __builtin_amdgcn_mfma_f32_16x16x32_bf16(af[i], wf[j], acc[i][j], 0, 0, 0);
    }
  };

  // prologue: stage t=0 into buf 0 (8 gloads outstanding)
#pragma unroll
  for (int i = 0; i < 4; ++i) {
    gload_lds16(A0 + a_goff[i],   &ldsA[0][s_lds[i]]);
    gload_lds16(Wrow + w_goff[i], &ldsW[0][s_lds[i]]);
  }

  for (int t = 0; t < nt - 1; ++t) {
    const int p   = t & 1;
    const int nxt = p ^ 1;
    int n2  = (t + 1) >> 2;
    int kk2 = ((t + 1) & 3) * 64;
    const unsigned short* An = A0 + (long)n2 * BD + kk2;
    const unsigned short* Wn = Wrow + (long)n2 * (DD * DD) + kk2;
#pragma unroll
    for (int i = 0; i < 4; ++i) {
      gload_lds16(An + a_goff[i], &ldsA[nxt][s_lds[i]]);
      gload_lds16(Wn + w_goff[i], &ldsW[nxt][s_lds[i]]);
    }
    asm volatile("s_waitcnt vmcnt(8)" ::: "memory");
    __builtin_amdgcn_s_barrier();
    compute(p);
    __builtin_amdgcn_s_barrier();
  }
  asm volatile("s_waitcnt vmcnt(0)" ::: "memory");
  __builtin_amdgcn_s_barrier();
  compute((nt - 1) & 1);

  // epilogue
  const int rowbase = brow0 + wr * 64;
  const int colbase = ecol0 + wc * 64;
  if (slot >= 0) {
    // raw fp32 partial, no bias/relu
    float* Pd = P + (long)slot * BD;
#pragma unroll
    for (int i = 0; i < 4; ++i) {
#pragma unroll
      for (int r = 0; r < 4; ++r) {
        const int row = rowbase + i * 16 + ((lane >> 4) << 2) + r;
        const long rb = (long)row * DD + colbase + (lane & 15);
#pragma unroll
        for (int j = 0; j < 4; ++j) Pd[rb + j * 16] = acc[i][j][r];
      }
    }
  } else {
    const long outbase = (long)m * BD;
    float bv[4];
#pragma unroll
    for (int j = 0; j < 4; ++j)
      bv[j] = bias_full[m * DD + colbase + j * 16 + (lane & 15)];
#pragma unroll
    for (int i = 0; i < 4; ++i) {
#pragma unroll
      for (int r = 0; r < 4; ++r) {
        const int row = rowbase + i * 16 + ((lane >> 4) << 2) + r;
        const long rb = outbase + (long)row * DD + colbase + (lane & 15);
#pragma unroll
        for (int j = 0; j < 4; ++j) {
          float v = acc[i][j][r] + bv[j];
          v = v > 0.f ? v : 0.f;
          if (OUT_BF16) ((unsigned short*)Out)[rb + j * 16] = f2bf(v);
          else          ((float*)Out)[rb + j * 16] = v;
        }
      }
    }
  }
}

// combine: for m=7..15, out = relu(P[2k]+P[2k+1]+bias_full[m]); grid 9*256
template <int OUT_BF16>
__global__ void combine_kernel(const float* __restrict__ P,
                               const float* __restrict__ bias_full,
                               void* __restrict__ Out) {
  int gid = blockIdx.x;
  int mi  = gid >> 8;            // 0..8
  int m   = mi + 7;
  long i0 = ((long)(gid & 255) * 256 + threadIdx.x) * 8;
  const float* P0 = P + (long)(2 * mi) * BD + i0;
  const float* P1 = P0 + BD;
  int col = (int)(i0 & 255);
  float4 a0 = *(const float4*)P0, a1 = *(const float4*)(P0 + 4);
  float4 b0 = *(const float4*)P1, b1 = *(const float4*)(P1 + 4);
  float4 c0 = *(const float4*)(bias_full + m * DD + col);
  float4 c1 = *(const float4*)(bias_full + m * DD + col + 4);
  float v[8] = {a0.x+b0.x+c0.x, a0.y+b0.y+c0.y, a0.z+b0.z+c0.z, a0.w+b0.w+c0.w,
                a1.x+b1.x+c1.x, a1.y+b1.y+c1.y, a1.z+b1.z+c1.z, a1.w+b1.w+c1.w};
#pragma unroll
  for (int k = 0; k < 8; ++k) v[k] = v[k] > 0.f ? v[k] : 0.f;
  long o = (long)m * BD + i0;
  if (OUT_BF16) {
    bfv8 t;
#pragma unroll
    for (int k = 0; k < 8; ++k) t[k] = (__bf16)v[k];
    *(bf16x8*)((unsigned short*)Out + o) = __builtin_bit_cast(bf16x8, t);
  } else {
    float* op = (float*)Out + o;
    *(float4*)op       = (float4){v[0], v[1], v[2], v[3]};
    *(float4*)(op + 4) = (float4){v[4], v[5], v[6], v[7]};
  }
}

// ---------------- v4 GEMM (proven 76us) — iter1 always; iters 2/3 fallback ----------------

template <int OUT_BF16, int TAG>
__global__ __launch_bounds__(256, 2) void gemm_step2(
    const unsigned short* __restrict__ A,
    const unsigned short* __restrict__ Wb,
    const float* __restrict__ bias,
    int bias_stride, long a_nstride, int nb_mode,
    void* __restrict__ Out)
{
  __shared__ unsigned short ldsA[2][128 * 64];
  __shared__ unsigned short ldsW[2][128 * 64];

  const int tid  = threadIdx.x;
  const int wave = tid >> 6;
  const int lane = tid & 63;

  int bid = blockIdx.x;
  int swz = (bid & 7) * 64 + (bid >> 3);
  int mi_ = swz >> 5;
  const int m = (int)((0x8796A5B4C3D2E1F0ULL >> (mi_ * 4)) & 15);
  int rest = swz & 31;
  const int btile = rest >> 1;
  const int etile = rest & 1;
  const int nb = nb_mode ? ((m + 2 < NBLK) ? m + 2 : NBLK) : 1;
  const int nt = nb << 2;

  const int brow0 = btile * 128;
  const int ecol0 = etile * 128;
  const int wr = (wave >> 1) & 1;
  const int wc = wave & 1;

  long a_goff[4], w_goff[4];
  int  s_lds[4];
#pragma unroll
  for (int i = 0; i < 4; ++i) {
    int inst  = wave * 4 + i;
    int row   = inst * 8 + (lane >> 3);
    int chunk = (lane & 7) ^ (row & 7);
    a_goff[i] = (long)(brow0 + row) * DD + chunk * 8;
    w_goff[i] = (long)(ecol0 + row) * DD + chunk * 8;
    s_lds[i]  = inst * 512;
  }

  int offA[4][2], offW[4][2];
#pragma unroll
  for (int f = 0; f < 4; ++f) {
    int ra = wr * 64 + f * 16 + (lane & 15);
    int rw = wc * 64 + f * 16 + (lane & 15);
#pragma unroll
    for (int ks = 0; ks < 2; ++ks) {
      int byteoff = ks * 64 + (lane >> 4) * 16;
      offA[f][ks] = ra * 64 + ((byteoff ^ ((ra & 7) << 4)) >> 1);
      offW[f][ks] = rw * 64 + ((byteoff ^ ((rw & 7) << 4)) >> 1);
    }
  }

  f32x4 acc[4][4];
#pragma unroll
  for (int i = 0; i < 4; ++i)
#pragma unroll
    for (int j = 0; j < 4; ++j) acc[i][j] = (f32x4){0.f, 0.f, 0.f, 0.f};

  const unsigned short* Wrow = Wb + (long)Pofs[m] * (DD * DD);

  auto compute = [&](int p) {
#pragma unroll
    for (int ks = 0; ks < 2; ++ks) {
      bf16x8 af[4], wf[4];
#pragma unroll
      for (int f = 0; f < 4; ++f) af[f] = *(const bf16x8*)&ldsA[p][offA[f][ks]];
#pragma unroll
      for (int f = 0; f < 4; ++f) wf[f] = *(const bf16x8*)&ldsW[p][offW[f][ks]];
#pragma unroll
      for (int i = 0; i < 4; ++i)
#pragma unroll
        for (int j = 0; j < 4; ++j)
          acc[i][j] = __builtin_amdgcn_mfma_f32_16x16x32_bf16(af[i], wf[j], acc[i][j], 0, 0, 0);
    }
  };

#pragma unroll
  for (int i = 0; i < 4; ++i) {
    gload_lds16(A + a_goff[i],    &ldsA[0][s_lds[i]]);
    gload_lds16(Wrow + w_goff[i], &ldsW[0][s_lds[i]]);
  }

  for (int t = 0; t < nt - 1; ++t) {
    const int p   = t & 1;
    const int nxt = p ^ 1;
    int n2  = (t + 1) >> 2;
    int kk2 = ((t + 1) & 3) * 64;
    const unsigned short* An = A + (long)n2 * a_nstride + kk2;
    const unsigned short* Wn = Wrow + (long)n2 * (DD * DD) + kk2;
#pragma unroll
    for (int i = 0; i < 4; ++i) {
      gload_lds16(An + a_goff[i], &ldsA[nxt][s_lds[i]]);
      gload_lds16(Wn + w_goff[i], &ldsW[nxt][s_lds[i]]);
    }
    asm volatile("s_waitcnt vmcnt(8)" ::: "memory");
    __builtin_amdgcn_s_barrier();
    compute(p);
    __builtin_amdgcn_s_barrier();
  }
  asm volatile("s_waitcnt vmcnt(0)" ::: "memory");
  __builtin_amdgcn_s_barrier();
  compute((nt - 1) & 1);

  const long outbase = (long)m * BD;
  const int  rowbase = brow0 + wr * 64;
  const int  colbase = ecol0 + wc * 64;
  float bv[4];
#pragma unroll
  for (int j = 0; j < 4; ++j)
    bv[j] = bias[m * bias_stride + colbase + j * 16 + (lane & 15)];
#pragma unroll
  for (int i = 0; i < 4; ++i) {
#pragma unroll
    for (int r = 0; r < 4; ++r) {
      const int row = rowbase + i * 16 + ((lane >> 4) << 2) + r;
      const long rb = outbase + (long)row * DD + colbase + (lane & 15);
#pragma unroll
      for (int j = 0; j < 4; ++j) {
        float v = acc[i][j][r] + bv[j];
        v = v > 0.f ? v : 0.f;
        if (OUT_BF16) ((unsigned short*)Out)[rb + j * 16] = f2bf(v);
        else          ((float*)Out)[rb + j * 16] = v;
      }
    }
  }
}

// ---------------- launcher ----------------

extern "C" void kernel_launch(void* const* d_in, const int* in_sizes, int n_in,
                              void* d_out, int out_size, void* d_ws, size_t ws_size,
                              hipStream_t stream) {
  const float* x0 = (const float*)d_in[0];
  const float* W  = (const float*)d_in[1];
  const float* b  = (const float*)d_in[2];
  float* out = (float*)d_out;

  char* ws = (char*)d_ws;
  unsigned short* x0b = (unsigned short*)ws;                    // 1 MB
  unsigned short* Y0  = (unsigned short*)(ws + (1ull << 20));   // 16 MB
  unsigned short* Y1  = (unsigned short*)(ws + (17ull << 20));  // 16 MB
  unsigned short* Wb  = (unsigned short*)(ws + (33ull << 20));  // 18.9 MB
  float* bias_full    = (float*)(ws + (52ull << 20));           // 16 KB
  float* Part         = (float*)(ws + (53ull << 20));           // 18 x 2MB = 36 MB

  const size_t need_v4    = (52ull << 20) + 16384;
  const size_t need_split = (53ull << 20) + 18ull * BD * 4;

  cvt_x0_kernel<<<512, 256, 0, stream>>>(x0, x0b);
  bias_full_kernel<<<16, 256, 0, stream>>>(b, bias_full);
  cvt_W_kernel<<<151 * 32, 256, 0, stream>>>(W, Wb);

  // iter 1 (nb=1 everywhere): proven v4 kernel, bias = b[m,0,:]
  gemm_step2<1, 1><<<512, 256, 0, stream>>>(x0b, Wb, b, NBLK * DD, 0L, 0, (void*)Y0);

  if (ws_size >= need_split) {
    // iter 2: split-K units + combine -> Y1 (bf16)
    gemm_unit<1, 2><<<800, 256, 0, stream>>>(Y0, Wb, bias_full, Part, (void*)Y1);
    combine_kernel<1><<<9 * 256, 256, 0, stream>>>(Part, bias_full, (void*)Y1);
    // iter 3: split-K units + combine -> d_out (fp32)
    gemm_unit<0, 3><<<800, 256, 0, stream>>>(Y1, Wb, bias_full, Part, (void*)out);
    combine_kernel<0><<<9 * 256, 256, 0, stream>>>(Part, bias_full, (void*)out);
  } else if (ws_size >= need_v4) {
    gemm_step2<1, 2><<<512, 256, 0, stream>>>(Y0, Wb, bias_full, DD, (long)BD, 1, (void*)Y1);
    gemm_step2<0, 3><<<512, 256, 0, stream>>>(Y1, Wb, bias_full, DD, (long)BD, 1, (void*)out);
  }
}